// Round 12
// baseline (308.018 us; speedup 1.0000x reference)
//
#include <hip/hip_runtime.h>
#include <hip/hip_bf16.h>
#include <math.h>

#define C 128
#define H 4
#define LMAX 64
#define EPS 1e-5f
#define ISQ 0.17677669529663687f   // 1/sqrt(32)

using short8  = __attribute__((ext_vector_type(8))) short;
using short4v = __attribute__((ext_vector_type(4))) short;
using f32x4   = __attribute__((ext_vector_type(4))) float;

__device__ __forceinline__ float wsum(float v){
  #pragma unroll
  for (int o = 32; o > 0; o >>= 1) v += __shfl_xor(v, o, 64);
  return v;
}
__device__ __forceinline__ float wmax(float v){
  #pragma unroll
  for (int o = 32; o > 0; o >>= 1) v = fmaxf(v, __shfl_xor(v, o, 64));
  return v;
}
__device__ __forceinline__ short f2bs(float f){
  __hip_bfloat16 b = __float2bfloat16(f);   // RNE
  union { __hip_bfloat16 b; short u; } cv; cv.b = b; return cv.u;
}
__device__ __forceinline__ float b2f(short u){
  return __uint_as_float(((unsigned)(unsigned short)u) << 16);
}

// ---- weight fragments: B-operand layout for mfma_f32_16x16x32_bf16 ----
// lane l, j -> W[kt*32 + (l>>4)*8 + j][nt*16 + (l&15)]
__global__ void prep_wfrag(const float* __restrict__ Wq, const float* __restrict__ Wk,
                           const float* __restrict__ Wv, const float* __restrict__ Wo,
                           const float* __restrict__ Wlin, short* __restrict__ wf){
  int bid = blockIdx.x, l = threadIdx.x;
  int tile = bid & 31, mb = bid >> 5;       // mb = mat*4+blk, 0..19
  int mat = mb >> 2, blk = mb & 3;
  const float* W = (mat==0?Wq : mat==1?Wk : mat==2?Wv : mat==3?Wo : Wlin) + blk*C*C;
  int nt = tile >> 2, kt = tile & 3;
  int col = nt*16 + (l & 15);
  int k0  = kt*32 + ((l >> 4) << 3);
  short8 v;
  #pragma unroll
  for (int j = 0; j < 8; j++) v[j] = f2bs(W[(k0 + j)*C + col]);
  *(short8*)(wf + ((size_t)mb*32 + tile)*512 + (size_t)l*8) = v;
}

__global__ void prep_qrow(const float* __restrict__ seed, const float* __restrict__ Wq,
                          const float* __restrict__ bq, float* __restrict__ qrow){
  int t = threadIdx.x;
  const float* wq2 = Wq + 2*C*C;
  float acc = bq[2*C + t];
  #pragma unroll 4
  for (int k = 0; k < C; k++) acc = fmaf(seed[k], wq2[k*C + t], acc);
  qrow[t] = acc;
}

// ---- segment bounds + class ranks ----
__global__ void seg_kernel(const int* __restrict__ gidx, int E, int G,
                           int* __restrict__ starts, int* __restrict__ counts,
                           int* __restrict__ cnt, int* __restrict__ gcr){
  int g = blockIdx.x * blockDim.x + threadIdx.x;
  if (g >= G) return;
  int lo = 0, hi = E;
  while (lo < hi){ int m = (lo + hi) >> 1; if (gidx[m] < g) lo = m + 1; else hi = m; }
  int s = lo; hi = E;
  while (lo < hi){ int m = (lo + hi) >> 1; if (gidx[m] < g + 1) lo = m + 1; else hi = m; }
  starts[g] = s;
  int c_ = lo - s; counts[g] = c_;
  int L = c_ > LMAX ? LMAX : c_; if (L < 1) L = 1;
  int cl = (L - 1) >> 4;
  int r = atomicAdd(&cnt[cl], 1);
  gcr[g] = (cl << 28) | r;
}

// ---- bin assignment from class ranks (deterministic per gene output) ----
__global__ void fill_kernel(int G, const int* __restrict__ cnt, const int* __restrict__ gcr,
                            int* __restrict__ binfo, int* __restrict__ nbins){
  int g = blockIdx.x * blockDim.x + threadIdx.x;
  if (g >= G) return;
  int nb1 = (cnt[0] + 3) >> 2, nb2 = (cnt[1] + 1) >> 1, nb3 = cnt[2];
  if (g == 0) *nbins = nb1 + nb2 + nb3 + cnt[3];
  int v = gcr[g]; int cl = v >> 28; int r = v & 0x0FFFFFFF;
  int bin, slot;
  if      (cl == 0){ bin = r >> 2;             slot = r & 3; }
  else if (cl == 1){ bin = nb1 + (r >> 1);     slot = (r & 1) * 2; }
  else if (cl == 2){ bin = nb1 + nb2 + r;      slot = 0; }
  else             { bin = nb1 + nb2 + nb3 + r; slot = 0; }
  binfo[bin*4 + slot] = g;
}

__device__ __forceinline__ f32x4 mfma4(short8 a0, short8 a1, short8 a2, short8 a3,
                                       const short* __restrict__ wf, int nt, int l){
  f32x4 acc = {0.f, 0.f, 0.f, 0.f};
  acc = __builtin_amdgcn_mfma_f32_16x16x32_bf16(a0, *(const short8*)(wf + ((nt*4+0)*64 + l)*8), acc, 0,0,0);
  acc = __builtin_amdgcn_mfma_f32_16x16x32_bf16(a1, *(const short8*)(wf + ((nt*4+1)*64 + l)*8), acc, 0,0,0);
  acc = __builtin_amdgcn_mfma_f32_16x16x32_bf16(a2, *(const short8*)(wf + ((nt*4+2)*64 + l)*8), acc, 0,0,0);
  acc = __builtin_amdgcn_mfma_f32_16x16x32_bf16(a3, *(const short8*)(wf + ((nt*4+3)*64 + l)*8), acc, 0,0,0);
  return acc;
}

// LN over 64 rows x 128 cols: 4 threads per row, shfl_xor(1,2) group reduce.
// row = t>>2 is wave-row-aligned: wave w handles rows [w*16, w*16+16).
__device__ __forceinline__ void ln_rows(const short (*src)[136], short (*dst)[136],
                                        const float* __restrict__ gg,
                                        const float* __restrict__ bb, int t){
  int row = t >> 2, q4 = t & 3;
  float v[32];
  float sm = 0.f;
  #pragma unroll
  for (int kk = 0; kk < 32; ++kk){
    float x = b2f(src[row][q4*32 + kk]);
    v[kk] = x; sm += x;
  }
  sm += __shfl_xor(sm, 1);
  sm += __shfl_xor(sm, 2);
  float mean = sm * (1.f/128.f);
  float s2 = 0.f;
  #pragma unroll
  for (int kk = 0; kk < 32; ++kk){ float d = v[kk] - mean; s2 += d*d; }
  s2 += __shfl_xor(s2, 1);
  s2 += __shfl_xor(s2, 2);
  float rs = rsqrtf(s2*(1.f/128.f) + EPS);
  #pragma unroll
  for (int kk = 0; kk < 32; ++kk){
    int col = q4*32 + kk;
    dst[row][col] = f2bs((v[kk] - mean)*rs*gg[col] + bb[col]);
  }
}

__global__ __launch_bounds__(256, 2) void gene_bin_kernel(
  const float* __restrict__ RF, const short* __restrict__ wfrag,
  const float* __restrict__ qrow,
  const float* __restrict__ Wv, const float* __restrict__ Wo,
  const float* __restrict__ Wlin, const float* __restrict__ seed,
  const float* __restrict__ bq, const float* __restrict__ bk,
  const float* __restrict__ bv, const float* __restrict__ bo,
  const float* __restrict__ blin,
  const float* __restrict__ g1, const float* __restrict__ b1,
  const float* __restrict__ g2, const float* __restrict__ b2,
  const int* __restrict__ rxn_idx, const int* __restrict__ starts,
  const int* __restrict__ counts, const int* __restrict__ binfo,
  const int* __restrict__ meta, float* __restrict__ out)
{
  if ((int)blockIdx.x >= meta[0]) return;
  __shared__ short xb[64][136];            // activations (residual source)
  __shared__ short qb[64][136];            // Q, then attn-out (wave-row-private after barA)
  __shared__ short kb[64][136];            // K, FF temp, PMA K; own rows reused as fp32 tail scratch
  __shared__ short vt[128][72];            // V^T: vt[d][key]
  __shared__ __align__(16) short sc[64][72]; // logits -> probs (wave-row-private); later fp32 PMA probs
  __shared__ float qrl[C];
  __shared__ int mg[4], mL[4], ms0[4], mbase[4];

  const int bin = blockIdx.x;
  const int t = threadIdx.x, w = t >> 6, l = t & 63;
  const int hi = l >> 4, c = l & 15;

  if (t == 0){
    int s = 0;
    while (s < 4){
      int g = binfo[bin*4 + s];
      if (g >= 0){
        int Lg = counts[g]; if (Lg > LMAX) Lg = LMAX;
        int ntg = (Lg + 15) >> 4;
        for (int u = 0; u < ntg; ++u){ mg[s+u] = g; mL[s+u] = Lg; ms0[s+u] = starts[g]; mbase[s+u] = s; }
        s += ntg;
      } else { mg[s] = -1; mL[s] = 0; ms0[s] = 0; mbase[s] = s; s++; }
    }
  }
  if (t < C) qrl[t] = qrow[t];
  __syncthreads();

  // ---- stage rows (bf16), zero pads; zero sc once (cross-gene cols stay 0 forever) ----
  for (int idx = t; idx < 64*16; idx += 256){
    int row = idx >> 4, ch = idx & 15;
    int s = row >> 4;
    int g = mg[s];
    int ro = row - mbase[s]*16;
    short8 u = {0,0,0,0,0,0,0,0};
    if (g >= 0 && ro < mL[s]){
      int rr = rxn_idx[ms0[s] + ro];
      const float* src = RF + (size_t)rr*C + ch*8;
      float4 v0 = *(const float4*)(src);
      float4 v1 = *(const float4*)(src + 4);
      u[0]=f2bs(v0.x); u[1]=f2bs(v0.y); u[2]=f2bs(v0.z); u[3]=f2bs(v0.w);
      u[4]=f2bs(v1.x); u[5]=f2bs(v1.y); u[6]=f2bs(v1.z); u[7]=f2bs(v1.w);
    }
    *(short8*)&xb[row][ch*8] = u;
  }
  {
    short8 z = {0,0,0,0,0,0,0,0};
    for (int idx = t; idx < 64*9; idx += 256){
      int row = idx / 9, ch = idx - row*9;
      *(short8*)&sc[row][ch*8] = z;
    }
  }
  __syncthreads();

  const int myg = mg[w];

  // ================= encoder SABs (blk 0,1) =================
  for (int blk = 0; blk < 2; ++blk){
    // ---- QKV projections (nt-split across waves) ----
    {
      short8 ax[4][4];
      #pragma unroll
      for (int mt = 0; mt < 4; ++mt)
        #pragma unroll
        for (int kk = 0; kk < 4; ++kk)
          ax[mt][kk] = *(const short8*)&xb[mt*16 + c][kk*32 + hi*8];
      #pragma unroll
      for (int i = 0; i < 6; ++i){
        int pr = w + 4*i;                 // 0..23 = (mat 0..2) x (nt 0..7)
        int mat = pr >> 3, nt = pr & 7;
        const short* wfm = wfrag + (size_t)(mat*4 + blk)*16384;
        const float* bias = (mat == 0 ? bq : mat == 1 ? bk : bv);
        int col = nt*16 + c;
        float bb = bias[blk*C + col];
        #pragma unroll
        for (int mt = 0; mt < 4; ++mt){
          f32x4 acc = mfma4(ax[mt][0], ax[mt][1], ax[mt][2], ax[mt][3], wfm, nt, l);
          if (mat == 2){
            short4v pk;
            #pragma unroll
            for (int r = 0; r < 4; r++) pk[r] = f2bs(acc[r] + bb);
            *(short4v*)&vt[col][mt*16 + hi*4] = pk;     // transposed
          } else if (mat == 0){
            #pragma unroll
            for (int r = 0; r < 4; r++) qb[mt*16 + hi*4 + r][col] = f2bs(acc[r] + bb);
          } else {
            #pragma unroll
            for (int r = 0; r < 4; r++) kb[mt*16 + hi*4 + r][col] = f2bs(acc[r] + bb);
          }
        }
      }
    }
    __syncthreads();   // bar A: Q,K,V visible block-wide

    // ---- attention: wave w owns row-block mt=w -> whole head loop is wave-private ----
    for (int h = 0; h < H; ++h){
      if (myg >= 0){
        short8 a = *(const short8*)&qb[w*16 + c][h*32 + hi*8];
        #pragma unroll
        for (int kt = 0; kt < 4; ++kt){
          if (mg[kt] == myg){
            short8 b = *(const short8*)&kb[kt*16 + c][h*32 + hi*8];
            f32x4 acc = {0.f, 0.f, 0.f, 0.f};
            acc = __builtin_amdgcn_mfma_f32_16x16x32_bf16(a, b, acc, 0,0,0);
            #pragma unroll
            for (int r = 0; r < 4; r++) sc[w*16 + hi*4 + r][kt*16 + c] = f2bs(acc[r] * ISQ);
          }
        }
      }
      // masked softmax in-place: row = t>>2 (wave-row-local)
      {
        int row = t >> 2, q4 = t & 3;
        int s = row >> 4;
        if (mg[s] >= 0){
          int kbeg = mbase[s]*16;
          int kend = kbeg + mL[s];
          int send = kbeg + (((mL[s] + 15) >> 4) << 4);
          int b0 = q4*16;
          float e[16];
          float mx = -3.4e38f;
          #pragma unroll
          for (int kk = 0; kk < 16; ++kk){
            int col = b0 + kk;
            bool ok = (col >= kbeg) && (col < kend);
            float lg = ok ? b2f(sc[row][col]) : -3.4e38f;
            e[kk] = lg;
            mx = fmaxf(mx, lg);
          }
          mx = fmaxf(mx, __shfl_xor(mx, 1));
          mx = fmaxf(mx, __shfl_xor(mx, 2));
          float sm = 0.f;
          #pragma unroll
          for (int kk = 0; kk < 16; ++kk){
            int col = b0 + kk;
            bool ok = (col >= kbeg) && (col < kend);
            float ee = ok ? __expf(e[kk] - mx) : 0.f;
            e[kk] = ee; sm += ee;
          }
          sm += __shfl_xor(sm, 1);
          sm += __shfl_xor(sm, 2);
          float inv = 1.f / sm;
          #pragma unroll
          for (int kk = 0; kk < 16; ++kk){
            int col = b0 + kk;
            if (col >= kbeg && col < send)
              sc[row][col] = f2bs((col < kend) ? e[kk]*inv : 0.f);
          }
        }
      }
      // PV: wave w owns mt=w
      if (myg >= 0){
        #pragma unroll
        for (int dt = 0; dt < 2; ++dt){
          f32x4 acc = {0.f, 0.f, 0.f, 0.f};
          #pragma unroll
          for (int ks = 0; ks < 2; ++ks){
            short8 a = *(const short8*)&sc[w*16 + c][ks*32 + hi*8];
            short8 b = *(const short8*)&vt[h*32 + dt*16 + c][ks*32 + hi*8];
            acc = __builtin_amdgcn_mfma_f32_16x16x32_bf16(a, b, acc, 0,0,0);
          }
          int col = h*32 + dt*16 + c;
          #pragma unroll
          for (int r = 0; r < 4; r++) qb[w*16 + hi*4 + r][col] = f2bs(acc[r]);
        }
      }
    }

    // ---- Wo + bo + residual -> xb (own rows) ----
    {
      short8 aw[4];
      #pragma unroll
      for (int kk = 0; kk < 4; kk++) aw[kk] = *(const short8*)&qb[w*16 + c][kk*32 + hi*8];
      const short* wfo = wfrag + (size_t)(3*4 + blk)*16384;
      #pragma unroll 2
      for (int nt = 0; nt < 8; ++nt){
        int col = nt*16 + c;
        f32x4 acc = mfma4(aw[0], aw[1], aw[2], aw[3], wfo, nt, l);
        float bb = bo[blk*C + col];
        #pragma unroll
        for (int r = 0; r < 4; r++){
          int row = w*16 + hi*4 + r;
          xb[row][col] = f2bs(acc[r] + bb + b2f(xb[row][col]));
        }
      }
    }
    ln_rows(xb, xb, g1 + blk*C, b1 + blk*C, t);
    __syncthreads();   // bar B: scores' cross-wave kb reads done before FF overwrites kb

    // ---- FF -> kb (own rows) ----
    {
      short8 aw[4];
      #pragma unroll
      for (int kk = 0; kk < 4; kk++) aw[kk] = *(const short8*)&xb[w*16 + c][kk*32 + hi*8];
      const short* wfl = wfrag + (size_t)(4*4 + blk)*16384;
      #pragma unroll 2
      for (int nt = 0; nt < 8; ++nt){
        int col = nt*16 + c;
        f32x4 acc = mfma4(aw[0], aw[1], aw[2], aw[3], wfl, nt, l);
        float bb = blin[blk*C + col];
        #pragma unroll
        for (int r = 0; r < 4; r++){
          int row = w*16 + hi*4 + r;
          kb[row][col] = f2bs(b2f(xb[row][col]) + fmaxf(acc[r] + bb, 0.f));
        }
      }
    }
    ln_rows(kb, xb, g2 + blk*C, b2 + blk*C, t);
    __syncthreads();   // bar C: next layer's QKV reads ALL xb rows
  }

  // ================= PMA: K,V projections + per-gene pooling + fused tail =================
  {
    short8 aw[4];
    #pragma unroll
    for (int kk = 0; kk < 4; kk++) aw[kk] = *(const short8*)&xb[w*16 + c][kk*32 + hi*8];
    const short* wfk2 = wfrag + (size_t)(1*4 + 2)*16384;
    const short* wfv2 = wfrag + (size_t)(2*4 + 2)*16384;
    #pragma unroll 2
    for (int nt = 0; nt < 8; ++nt){
      int col = nt*16 + c;
      f32x4 acc = mfma4(aw[0], aw[1], aw[2], aw[3], wfk2, nt, l);
      float bb = bk[2*C + col];
      #pragma unroll
      for (int r = 0; r < 4; r++) kb[w*16 + hi*4 + r][col] = f2bs(acc[r] + bb);
      acc = mfma4(aw[0], aw[1], aw[2], aw[3], wfv2, nt, l);
      bb = bv[2*C + col];
      short4v pk;
      #pragma unroll
      for (int r = 0; r < 4; r++) pk[r] = f2bs(acc[r] + bb);
      *(short4v*)&vt[col][w*16 + hi*4] = pk;
    }
  }
  __syncthreads();   // bar A': K',V' visible (pooling reads cross-wave rows/cols)

  {
    int g = mg[w];
    if (g >= 0 && mbase[w] == w){
      int L = mL[w];
      int row = w*16 + l;                // key row in kb / key col in vt
      float* ps = (float*)&sc[0][0];     // sc dead: alias as fp32 probs [slot*4+h][64]
      #pragma unroll
      for (int h = 0; h < 4; ++h){
        float a = -3.4e38f;
        if (l < L){
          float acc = 0.f;
          #pragma unroll 8
          for (int dd = 0; dd < 32; ++dd)
            acc = fmaf(b2f(kb[row][h*32 + dd]), qrl[h*32 + dd], acc);
          a = acc * ISQ;
        }
        float mx = wmax(a);
        float e = (l < L) ? __expf(a - mx) : 0.f;
        float s = wsum(e);
        ps[(w*4 + h)*64 + l] = e / s;
      }
      // PV pooling: lane l computes pooled dims d=l and d=l+64 (kept in regs)
      float p0, p1;
      {
        int h0 = l >> 5;
        float acc = 0.f;
        for (int kk = 0; kk < L; ++kk)
          acc = fmaf(ps[(w*4 + h0)*64 + kk], b2f(vt[l][w*16 + kk]), acc);
        p0 = acc;
        int d1 = l + 64, h1 = d1 >> 5;
        acc = 0.f;
        for (int kk = 0; kk < L; ++kk)
          acc = fmaf(ps[(w*4 + h1)*64 + kk], b2f(vt[d1][w*16 + kk]), acc);
        p1 = acc;
      }

      // ---- fused per-gene tail (R4-validated math): wave-private fp32 chain ----
      // scratch: own 16 kb rows (dead after pooling reads above) = 1088 floats
      float* fs  = (float*)&kb[w*16][0];
      float* fsA = fs;            // row0
      float* fsB = fs + 128;      // row1
      float* fsC = fs + 256;      // row2
      float o0, o1;

      fsB[l] = p0; fsB[64 + l] = p1;      // row1 = pooled
      // P1: row0 = row1 @ Wo2 + bo2 + seed
      {
        const float* Wm = Wo + 2*C*C;
        o0 = bo[2*C + l]; o1 = bo[2*C + 64 + l];
        #pragma unroll 4
        for (int k = 0; k < C; ++k){
          float x = fsB[k];
          o0 = fmaf(x, Wm[k*C + l], o0);
          o1 = fmaf(x, Wm[k*C + 64 + l], o1);
        }
        fsA[l]      = o0 + seed[l];
        fsA[64 + l] = o1 + seed[64 + l];
      }
      // LN1
      {
        float v0 = fsA[l], v1 = fsA[64 + l];
        float m = wsum(v0 + v1) * (1.f / C);
        float d0 = v0 - m, d1 = v1 - m;
        float va = wsum(d0*d0 + d1*d1) * (1.f / C);
        float rs = rsqrtf(va + EPS);
        fsA[l]      = d0 * rs * g1[2*C + l]      + b1[2*C + l];
        fsA[64 + l] = d1 * rs * g1[2*C + 64 + l] + b1[2*C + 64 + l];
      }
      // P2: row1 = row0 + relu(row0 @ Wlin2 + blin2)
      {
        const float* Wm = Wlin + 2*C*C;
        o0 = blin[2*C + l]; o1 = blin[2*C + 64 + l];
        #pragma unroll 4
        for (int k = 0; k < C; ++k){
          float x = fsA[k];
          o0 = fmaf(x, Wm[k*C + l], o0);
          o1 = fmaf(x, Wm[k*C + 64 + l], o1);
        }
        fsB[l]      = fsA[l]      + fmaxf(o0, 0.f);
        fsB[64 + l] = fsA[64 + l] + fmaxf(o1, 0.f);
      }
      // LN2 -> row0 = h3
      {
        float v0 = fsB[l], v1 = fsB[64 + l];
        float m = wsum(v0 + v1) * (1.f / C);
        float d0 = v0 - m, d1 = v1 - m;
        float va = wsum(d0*d0 + d1*d1) * (1.f / C);
        float rs = rsqrtf(va + EPS);
        fsA[l]      = d0 * rs * g2[2*C + l]      + b2[2*C + l];
        fsA[64 + l] = d1 * rs * g2[2*C + 64 + l] + b2[2*C + 64 + l];
      }
      // P3: row1 = h3 @ Wv3 + bv3
      {
        const float* Wm = Wv + 3*C*C;
        o0 = bv[3*C + l]; o1 = bv[3*C + 64 + l];
        #pragma unroll 4
        for (int k = 0; k < C; ++k){
          float x = fsA[k];
          o0 = fmaf(x, Wm[k*C + l], o0);
          o1 = fmaf(x, Wm[k*C + 64 + l], o1);
        }
        fsB[l] = o0; fsB[64 + l] = o1;
      }
      // P4: row2 = row1 @ Wo3 + bo3 + h3
      {
        const float* Wm = Wo + 3*C*C;
        o0 = bo[3*C + l]; o1 = bo[3*C + 64 + l];
        #pragma unroll 4
        for (int k = 0; k < C; ++k){
          float x = fsB[k];
          o0 = fmaf(x, Wm[k*C + l], o0);
          o1 = fmaf(x, Wm[k*C + 64 + l], o1);
        }
        fsC[l]      = o0 + fsA[l];
        fsC[64 + l] = o1 + fsA[64 + l];
      }
      // LN1_3 in place on row2
      {
        float v0 = fsC[l], v1 = fsC[64 + l];
        float m = wsum(v0 + v1) * (1.f / C);
        float d0 = v0 - m, d1 = v1 - m;
        float va = wsum(d0*d0 + d1*d1) * (1.f / C);
        float rs = rsqrtf(va + EPS);
        fsC[l]      = d0 * rs * g1[3*C + l]      + b1[3*C + l];
        fsC[64 + l] = d1 * rs * g1[3*C + 64 + l] + b1[3*C + 64 + l];
      }
      // P5: row1 = row2 + relu(row2 @ Wlin3 + blin3)
      {
        const float* Wm = Wlin + 3*C*C;
        o0 = blin[3*C + l]; o1 = blin[3*C + 64 + l];
        #pragma unroll 4
        for (int k = 0; k < C; ++k){
          float x = fsC[k];
          o0 = fmaf(x, Wm[k*C + l], o0);
          o1 = fmaf(x, Wm[k*C + 64 + l], o1);
        }
        fsB[l]      = fsC[l]      + fmaxf(o0, 0.f);
        fsB[64 + l] = fsC[64 + l] + fmaxf(o1, 0.f);
      }
      // LN2_3 + nan_to_num + store
      {
        float v0 = fsB[l], v1 = fsB[64 + l];
        float m = wsum(v0 + v1) * (1.f / C);
        float d0 = v0 - m, d1 = v1 - m;
        float va = wsum(d0*d0 + d1*d1) * (1.f / C);
        float rs = rsqrtf(va + EPS);
        float r0 = d0 * rs * g2[3*C + l]      + b2[3*C + l];
        float r1 = d1 * rs * g2[3*C + 64 + l] + b2[3*C + 64 + l];
        if (isnan(r0)) r0 = 0.f; else if (isinf(r0)) r0 = r0 > 0 ? 3.402823466e38f : -3.402823466e38f;
        if (isnan(r1)) r1 = 0.f; else if (isinf(r1)) r1 = r1 > 0 ? 3.402823466e38f : -3.402823466e38f;
        out[(size_t)g*C + l]      = r0;
        out[(size_t)g*C + 64 + l] = r1;
      }
    }
  }
}

extern "C" void kernel_launch(void* const* d_in, const int* in_sizes, int n_in,
                              void* d_out, int out_size, void* d_ws, size_t ws_size,
                              hipStream_t stream){
  const float* RF   = (const float*)d_in[0];
  const float* Wq   = (const float*)d_in[1];
  const float* Wk   = (const float*)d_in[2];
  const float* Wv   = (const float*)d_in[3];
  const float* Wo   = (const float*)d_in[4];
  const float* bq   = (const float*)d_in[5];
  const float* bk   = (const float*)d_in[6];
  const float* bv   = (const float*)d_in[7];
  const float* bo   = (const float*)d_in[8];
  const float* Wlin = (const float*)d_in[9];
  const float* blin = (const float*)d_in[10];
  const float* g1   = (const float*)d_in[11];
  const float* b1   = (const float*)d_in[12];
  const float* g2   = (const float*)d_in[13];
  const float* b2   = (const float*)d_in[14];
  const float* seed = (const float*)d_in[15];
  const int* rxn    = (const int*)d_in[16];
  const int* gidx   = (const int*)d_in[17];

  int E = in_sizes[16];
  int G = out_size / C;

  // ws layout
  char* base = (char*)d_ws;
  short* wfrag = (short*)base;                             // 655360 B
  float* qrow  = (float*)(base + 655360);                  // 512 B
  int*   meta  = (int*)(base + 655872);                    // 64 B: [0]=nbins, [1..4]=cnt
  int*   starts= (int*)(base + 655936);                    // 4G
  int*   counts= (int*)(base + 655936 + (size_t)4*G);      // 4G
  int*   gcr   = (int*)(base + 655936 + (size_t)8*G);      // 4G
  int*   binfo = (int*)(base + 655936 + (size_t)12*G);     // 16G

  hipMemsetAsync(meta, 0, 64, stream);
  hipMemsetAsync(binfo, 0xFF, (size_t)16*G, stream);
  prep_wfrag<<<640, 64, 0, stream>>>(Wq, Wk, Wv, Wo, Wlin, wfrag);
  prep_qrow<<<1, 128, 0, stream>>>(seed, Wq, bq, qrow);
  seg_kernel<<<(G + 255)/256, 256, 0, stream>>>(gidx, E, G, starts, counts, meta + 1, gcr);
  fill_kernel<<<(G + 255)/256, 256, 0, stream>>>(G, meta + 1, gcr, binfo, meta);
  gene_bin_kernel<<<G, 256, 0, stream>>>(RF, wfrag, qrow, Wv, Wo, Wlin, seed,
      bq, bk, bv, bo, blin, g1, b1, g2, b2, rxn, starts, counts, binfo, meta,
      (float*)d_out);
}

// Round 13
// 261.238 us; speedup vs baseline: 1.1791x; 1.1791x over previous
//
#include <hip/hip_runtime.h>
#include <hip/hip_bf16.h>
#include <math.h>

#define C 128
#define H 4
#define LMAX 64
#define EPS 1e-5f
#define ISQ 0.17677669529663687f   // 1/sqrt(32)

using short8  = __attribute__((ext_vector_type(8))) short;
using short4v = __attribute__((ext_vector_type(4))) short;
using f32x4   = __attribute__((ext_vector_type(4))) float;

__device__ __forceinline__ float wsum(float v){
  #pragma unroll
  for (int o = 32; o > 0; o >>= 1) v += __shfl_xor(v, o, 64);
  return v;
}
__device__ __forceinline__ float wmax(float v){
  #pragma unroll
  for (int o = 32; o > 0; o >>= 1) v = fmaxf(v, __shfl_xor(v, o, 64));
  return v;
}
__device__ __forceinline__ short f2bs(float f){
  __hip_bfloat16 b = __float2bfloat16(f);   // RNE
  union { __hip_bfloat16 b; short u; } cv; cv.b = b; return cv.u;
}
__device__ __forceinline__ float b2f(short u){
  return __uint_as_float(((unsigned)(unsigned short)u) << 16);
}

// ---- weight fragments: B-operand layout for mfma_f32_16x16x32_bf16 ----
// lane l, j -> W[kt*32 + (l>>4)*8 + j][nt*16 + (l&15)]
__global__ void prep_wfrag(const float* __restrict__ Wq, const float* __restrict__ Wk,
                           const float* __restrict__ Wv, const float* __restrict__ Wo,
                           const float* __restrict__ Wlin, short* __restrict__ wf){
  int bid = blockIdx.x, l = threadIdx.x;
  int tile = bid & 31, mb = bid >> 5;       // mb = mat*4+blk, 0..19
  int mat = mb >> 2, blk = mb & 3;
  const float* W = (mat==0?Wq : mat==1?Wk : mat==2?Wv : mat==3?Wo : Wlin) + blk*C*C;
  int nt = tile >> 2, kt = tile & 3;
  int col = nt*16 + (l & 15);
  int k0  = kt*32 + ((l >> 4) << 3);
  short8 v;
  #pragma unroll
  for (int j = 0; j < 8; j++) v[j] = f2bs(W[(k0 + j)*C + col]);
  *(short8*)(wf + ((size_t)mb*32 + tile)*512 + (size_t)l*8) = v;
}

__global__ void prep_qrow(const float* __restrict__ seed, const float* __restrict__ Wq,
                          const float* __restrict__ bq, float* __restrict__ qrow){
  int t = threadIdx.x;
  const float* wq2 = Wq + 2*C*C;
  float acc = bq[2*C + t];
  #pragma unroll 4
  for (int k = 0; k < C; k++) acc = fmaf(seed[k], wq2[k*C + t], acc);
  qrow[t] = acc;
}

// ---- segment bounds + class ranks ----
__global__ void seg_kernel(const int* __restrict__ gidx, int E, int G,
                           int* __restrict__ starts, int* __restrict__ counts,
                           int* __restrict__ cnt, int* __restrict__ gcr){
  int g = blockIdx.x * blockDim.x + threadIdx.x;
  if (g >= G) return;
  int lo = 0, hi = E;
  while (lo < hi){ int m = (lo + hi) >> 1; if (gidx[m] < g) lo = m + 1; else hi = m; }
  int s = lo; hi = E;
  while (lo < hi){ int m = (lo + hi) >> 1; if (gidx[m] < g + 1) lo = m + 1; else hi = m; }
  starts[g] = s;
  int c_ = lo - s; counts[g] = c_;
  int L = c_ > LMAX ? LMAX : c_; if (L < 1) L = 1;
  int cl = (L - 1) >> 4;
  int r = atomicAdd(&cnt[cl], 1);
  gcr[g] = (cl << 28) | r;
}

// ---- bin assignment from class ranks (deterministic per gene output) ----
__global__ void fill_kernel(int G, const int* __restrict__ cnt, const int* __restrict__ gcr,
                            int* __restrict__ binfo, int* __restrict__ nbins){
  int g = blockIdx.x * blockDim.x + threadIdx.x;
  if (g >= G) return;
  int nb1 = (cnt[0] + 3) >> 2, nb2 = (cnt[1] + 1) >> 1, nb3 = cnt[2];
  if (g == 0) *nbins = nb1 + nb2 + nb3 + cnt[3];
  int v = gcr[g]; int cl = v >> 28; int r = v & 0x0FFFFFFF;
  int bin, slot;
  if      (cl == 0){ bin = r >> 2;             slot = r & 3; }
  else if (cl == 1){ bin = nb1 + (r >> 1);     slot = (r & 1) * 2; }
  else if (cl == 2){ bin = nb1 + nb2 + r;      slot = 0; }
  else             { bin = nb1 + nb2 + nb3 + r; slot = 0; }
  binfo[bin*4 + slot] = g;
}

__device__ __forceinline__ f32x4 mfma4(short8 a0, short8 a1, short8 a2, short8 a3,
                                       const short* __restrict__ wf, int nt, int l){
  f32x4 acc = {0.f, 0.f, 0.f, 0.f};
  acc = __builtin_amdgcn_mfma_f32_16x16x32_bf16(a0, *(const short8*)(wf + ((nt*4+0)*64 + l)*8), acc, 0,0,0);
  acc = __builtin_amdgcn_mfma_f32_16x16x32_bf16(a1, *(const short8*)(wf + ((nt*4+1)*64 + l)*8), acc, 0,0,0);
  acc = __builtin_amdgcn_mfma_f32_16x16x32_bf16(a2, *(const short8*)(wf + ((nt*4+2)*64 + l)*8), acc, 0,0,0);
  acc = __builtin_amdgcn_mfma_f32_16x16x32_bf16(a3, *(const short8*)(wf + ((nt*4+3)*64 + l)*8), acc, 0,0,0);
  return acc;
}

// LN over 64 rows x 128 cols: 4 threads per row, shfl_xor(1,2) group reduce.
// row = t>>2 is wave-row-aligned: wave w handles rows [w*16, w*16+16).
__device__ __forceinline__ void ln_rows(const short (*src)[136], short (*dst)[136],
                                        const float* __restrict__ gg,
                                        const float* __restrict__ bb, int t){
  int row = t >> 2, q4 = t & 3;
  float v[32];
  float sm = 0.f;
  #pragma unroll
  for (int kk = 0; kk < 32; ++kk){
    float x = b2f(src[row][q4*32 + kk]);
    v[kk] = x; sm += x;
  }
  sm += __shfl_xor(sm, 1);
  sm += __shfl_xor(sm, 2);
  float mean = sm * (1.f/128.f);
  float s2 = 0.f;
  #pragma unroll
  for (int kk = 0; kk < 32; ++kk){ float d = v[kk] - mean; s2 += d*d; }
  s2 += __shfl_xor(s2, 1);
  s2 += __shfl_xor(s2, 2);
  float rs = rsqrtf(s2*(1.f/128.f) + EPS);
  #pragma unroll
  for (int kk = 0; kk < 32; ++kk){
    int col = q4*32 + kk;
    dst[row][col] = f2bs((v[kk] - mean)*rs*gg[col] + bb[col]);
  }
}

__global__ __launch_bounds__(256, 2) void gene_bin_kernel(
  const float* __restrict__ RF, const short* __restrict__ wfrag,
  const float* __restrict__ qrow,
  const float* __restrict__ bq, const float* __restrict__ bk,
  const float* __restrict__ bv, const float* __restrict__ bo,
  const float* __restrict__ blin,
  const float* __restrict__ g1, const float* __restrict__ b1,
  const float* __restrict__ g2, const float* __restrict__ b2,
  const int* __restrict__ rxn_idx, const int* __restrict__ starts,
  const int* __restrict__ counts, const int* __restrict__ binfo,
  const int* __restrict__ meta, float* __restrict__ pooled)
{
  if ((int)blockIdx.x >= meta[0]) return;
  __shared__ short xb[64][136];            // activations (residual source)
  __shared__ short qb[64][136];            // Q, then attn-out (wave-row-private after barA)
  __shared__ short kb[64][136];            // K, then FF temp, then PMA K
  __shared__ short vt[128][72];            // V^T: vt[d][key]
  __shared__ __align__(16) short sc[64][72]; // logits -> probs (wave-row-private); later fp32 PMA probs
  __shared__ float qrl[C];
  __shared__ int mg[4], mL[4], ms0[4], mbase[4];

  const int bin = blockIdx.x;
  const int t = threadIdx.x, w = t >> 6, l = t & 63;
  const int hi = l >> 4, c = l & 15;

  if (t == 0){
    int s = 0;
    while (s < 4){
      int g = binfo[bin*4 + s];
      if (g >= 0){
        int Lg = counts[g]; if (Lg > LMAX) Lg = LMAX;
        int ntg = (Lg + 15) >> 4;
        for (int u = 0; u < ntg; ++u){ mg[s+u] = g; mL[s+u] = Lg; ms0[s+u] = starts[g]; mbase[s+u] = s; }
        s += ntg;
      } else { mg[s] = -1; mL[s] = 0; ms0[s] = 0; mbase[s] = s; s++; }
    }
  }
  if (t < C) qrl[t] = qrow[t];
  __syncthreads();

  // ---- stage rows (bf16), zero pads; zero sc once (cross-gene cols stay 0 forever) ----
  for (int idx = t; idx < 64*16; idx += 256){
    int row = idx >> 4, ch = idx & 15;
    int s = row >> 4;
    int g = mg[s];
    int ro = row - mbase[s]*16;
    short8 u = {0,0,0,0,0,0,0,0};
    if (g >= 0 && ro < mL[s]){
      int rr = rxn_idx[ms0[s] + ro];
      const float* src = RF + (size_t)rr*C + ch*8;
      float4 v0 = *(const float4*)(src);
      float4 v1 = *(const float4*)(src + 4);
      u[0]=f2bs(v0.x); u[1]=f2bs(v0.y); u[2]=f2bs(v0.z); u[3]=f2bs(v0.w);
      u[4]=f2bs(v1.x); u[5]=f2bs(v1.y); u[6]=f2bs(v1.z); u[7]=f2bs(v1.w);
    }
    *(short8*)&xb[row][ch*8] = u;
  }
  {
    short8 z = {0,0,0,0,0,0,0,0};
    for (int idx = t; idx < 64*9; idx += 256){
      int row = idx / 9, ch = idx - row*9;
      *(short8*)&sc[row][ch*8] = z;
    }
  }
  __syncthreads();

  const int myg = mg[w];

  // ================= encoder SABs (blk 0,1) =================
  for (int blk = 0; blk < 2; ++blk){
    // ---- QKV projections (nt-split across waves) ----
    {
      short8 ax[4][4];
      #pragma unroll
      for (int mt = 0; mt < 4; ++mt)
        #pragma unroll
        for (int kk = 0; kk < 4; ++kk)
          ax[mt][kk] = *(const short8*)&xb[mt*16 + c][kk*32 + hi*8];
      #pragma unroll
      for (int i = 0; i < 6; ++i){
        int pr = w + 4*i;                 // 0..23 = (mat 0..2) x (nt 0..7)
        int mat = pr >> 3, nt = pr & 7;
        const short* wfm = wfrag + (size_t)(mat*4 + blk)*16384;
        const float* bias = (mat == 0 ? bq : mat == 1 ? bk : bv);
        int col = nt*16 + c;
        float bb = bias[blk*C + col];
        #pragma unroll
        for (int mt = 0; mt < 4; ++mt){
          f32x4 acc = mfma4(ax[mt][0], ax[mt][1], ax[mt][2], ax[mt][3], wfm, nt, l);
          if (mat == 2){
            short4v pk;
            #pragma unroll
            for (int r = 0; r < 4; r++) pk[r] = f2bs(acc[r] + bb);
            *(short4v*)&vt[col][mt*16 + hi*4] = pk;     // transposed
          } else if (mat == 0){
            #pragma unroll
            for (int r = 0; r < 4; r++) qb[mt*16 + hi*4 + r][col] = f2bs(acc[r] + bb);
          } else {
            #pragma unroll
            for (int r = 0; r < 4; r++) kb[mt*16 + hi*4 + r][col] = f2bs(acc[r] + bb);
          }
        }
      }
    }
    __syncthreads();   // bar A: Q,K,V visible block-wide

    // ---- attention: wave w owns row-block mt=w -> whole head loop is wave-private ----
    for (int h = 0; h < H; ++h){
      if (myg >= 0){
        short8 a = *(const short8*)&qb[w*16 + c][h*32 + hi*8];
        #pragma unroll
        for (int kt = 0; kt < 4; ++kt){
          if (mg[kt] == myg){
            short8 b = *(const short8*)&kb[kt*16 + c][h*32 + hi*8];
            f32x4 acc = {0.f, 0.f, 0.f, 0.f};
            acc = __builtin_amdgcn_mfma_f32_16x16x32_bf16(a, b, acc, 0,0,0);
            #pragma unroll
            for (int r = 0; r < 4; r++) sc[w*16 + hi*4 + r][kt*16 + c] = f2bs(acc[r] * ISQ);
          }
        }
      }
      // masked softmax in-place: row = t>>2 (wave-row-local)
      {
        int row = t >> 2, q4 = t & 3;
        int s = row >> 4;
        if (mg[s] >= 0){
          int kbeg = mbase[s]*16;
          int kend = kbeg + mL[s];
          int send = kbeg + (((mL[s] + 15) >> 4) << 4);
          int b0 = q4*16;
          float e[16];
          float mx = -3.4e38f;
          #pragma unroll
          for (int kk = 0; kk < 16; ++kk){
            int col = b0 + kk;
            bool ok = (col >= kbeg) && (col < kend);
            float lg = ok ? b2f(sc[row][col]) : -3.4e38f;
            e[kk] = lg;
            mx = fmaxf(mx, lg);
          }
          mx = fmaxf(mx, __shfl_xor(mx, 1));
          mx = fmaxf(mx, __shfl_xor(mx, 2));
          float sm = 0.f;
          #pragma unroll
          for (int kk = 0; kk < 16; ++kk){
            int col = b0 + kk;
            bool ok = (col >= kbeg) && (col < kend);
            float ee = ok ? __expf(e[kk] - mx) : 0.f;
            e[kk] = ee; sm += ee;
          }
          sm += __shfl_xor(sm, 1);
          sm += __shfl_xor(sm, 2);
          float inv = 1.f / sm;
          #pragma unroll
          for (int kk = 0; kk < 16; ++kk){
            int col = b0 + kk;
            if (col >= kbeg && col < send)
              sc[row][col] = f2bs((col < kend) ? e[kk]*inv : 0.f);
          }
        }
      }
      // PV: wave w owns mt=w
      if (myg >= 0){
        #pragma unroll
        for (int dt = 0; dt < 2; ++dt){
          f32x4 acc = {0.f, 0.f, 0.f, 0.f};
          #pragma unroll
          for (int ks = 0; ks < 2; ++ks){
            short8 a = *(const short8*)&sc[w*16 + c][ks*32 + hi*8];
            short8 b = *(const short8*)&vt[h*32 + dt*16 + c][ks*32 + hi*8];
            acc = __builtin_amdgcn_mfma_f32_16x16x32_bf16(a, b, acc, 0,0,0);
          }
          int col = h*32 + dt*16 + c;
          #pragma unroll
          for (int r = 0; r < 4; r++) qb[w*16 + hi*4 + r][col] = f2bs(acc[r]);
        }
      }
    }

    // ---- Wo + bo + residual -> xb (own rows) ----
    {
      short8 aw[4];
      #pragma unroll
      for (int kk = 0; kk < 4; kk++) aw[kk] = *(const short8*)&qb[w*16 + c][kk*32 + hi*8];
      const short* wfo = wfrag + (size_t)(3*4 + blk)*16384;
      #pragma unroll 2
      for (int nt = 0; nt < 8; ++nt){
        int col = nt*16 + c;
        f32x4 acc = mfma4(aw[0], aw[1], aw[2], aw[3], wfo, nt, l);
        float bb = bo[blk*C + col];
        #pragma unroll
        for (int r = 0; r < 4; r++){
          int row = w*16 + hi*4 + r;
          xb[row][col] = f2bs(acc[r] + bb + b2f(xb[row][col]));
        }
      }
    }
    ln_rows(xb, xb, g1 + blk*C, b1 + blk*C, t);
    __syncthreads();   // bar B: scores' cross-wave kb reads done before FF overwrites kb

    // ---- FF -> kb (own rows) ----
    {
      short8 aw[4];
      #pragma unroll
      for (int kk = 0; kk < 4; kk++) aw[kk] = *(const short8*)&xb[w*16 + c][kk*32 + hi*8];
      const short* wfl = wfrag + (size_t)(4*4 + blk)*16384;
      #pragma unroll 2
      for (int nt = 0; nt < 8; ++nt){
        int col = nt*16 + c;
        f32x4 acc = mfma4(aw[0], aw[1], aw[2], aw[3], wfl, nt, l);
        float bb = blin[blk*C + col];
        #pragma unroll
        for (int r = 0; r < 4; r++){
          int row = w*16 + hi*4 + r;
          kb[row][col] = f2bs(b2f(xb[row][col]) + fmaxf(acc[r] + bb, 0.f));
        }
      }
    }
    ln_rows(kb, xb, g2 + blk*C, b2 + blk*C, t);
    __syncthreads();   // bar C: next layer's QKV reads ALL xb rows
  }

  // ================= PMA: K,V projections + per-gene pooling =================
  {
    short8 aw[4];
    #pragma unroll
    for (int kk = 0; kk < 4; kk++) aw[kk] = *(const short8*)&xb[w*16 + c][kk*32 + hi*8];
    const short* wfk2 = wfrag + (size_t)(1*4 + 2)*16384;
    const short* wfv2 = wfrag + (size_t)(2*4 + 2)*16384;
    #pragma unroll 2
    for (int nt = 0; nt < 8; ++nt){
      int col = nt*16 + c;
      f32x4 acc = mfma4(aw[0], aw[1], aw[2], aw[3], wfk2, nt, l);
      float bb = bk[2*C + col];
      #pragma unroll
      for (int r = 0; r < 4; r++) kb[w*16 + hi*4 + r][col] = f2bs(acc[r] + bb);
      acc = mfma4(aw[0], aw[1], aw[2], aw[3], wfv2, nt, l);
      bb = bv[2*C + col];
      short4v pk;
      #pragma unroll
      for (int r = 0; r < 4; r++) pk[r] = f2bs(acc[r] + bb);
      *(short4v*)&vt[col][w*16 + hi*4] = pk;
    }
  }
  __syncthreads();   // bar A': K',V' visible (pooling reads cross-wave rows/cols)
  // pooling: wave w = slot w (if base slot of a gene)
  {
    int g = mg[w];
    if (g >= 0 && mbase[w] == w){
      int L = mL[w];
      int row = w*16 + l;                // key row in kb / key col in vt
      float* ps = (float*)&sc[0][0];     // sc dead: alias as fp32 probs [slot*4+h][64]
      #pragma unroll
      for (int h = 0; h < 4; ++h){
        float a = -3.4e38f;
        if (l < L){
          float acc = 0.f;
          #pragma unroll 8
          for (int dd = 0; dd < 32; ++dd)
            acc = fmaf(b2f(kb[row][h*32 + dd]), qrl[h*32 + dd], acc);
          a = acc * ISQ;
        }
        float mx = wmax(a);
        float e = (l < L) ? __expf(a - mx) : 0.f;
        float s = wsum(e);
        ps[(w*4 + h)*64 + l] = e / s;
      }
      #pragma unroll
      for (int half = 0; half < 2; ++half){
        int d = l + half*64;
        int h = d >> 5;
        float acc = 0.f;
        for (int kk = 0; kk < L; ++kk)
          acc = fmaf(ps[(w*4 + h)*64 + kk], b2f(vt[d][w*16 + kk]), acc);
        pooled[(size_t)g*C + d] = acc;
      }
    }
  }
}

// ================= fp32 batched tail: PMA post-attn + decoder SAB (16 genes/block, 8 waves) =================
__device__ __forceinline__ void gemmf(const float (*src)[132], const float* __restrict__ W,
                                      float (&o)[4], int col, int rg){
  #pragma unroll
  for (int r = 0; r < 4; ++r) o[r] = 0.f;
  #pragma unroll 8
  for (int k = 0; k < 128; ++k){
    float wv = W[k*C + col];
    #pragma unroll
    for (int r = 0; r < 4; ++r) o[r] = fmaf(src[rg*4 + r][k], wv, o[r]);
  }
}

__device__ __forceinline__ void ln16f(float (*buf)[132], const float* __restrict__ gg,
                                      const float* __restrict__ bb, int t){
  int row = t >> 4, cg = t & 15;
  float v[8]; float s = 0.f;
  #pragma unroll
  for (int k = 0; k < 8; ++k){ v[k] = buf[row][cg*8 + k]; s += v[k]; }
  s += __shfl_xor(s,1); s += __shfl_xor(s,2); s += __shfl_xor(s,4); s += __shfl_xor(s,8);
  float mean = s * (1.f/128.f);
  float q = 0.f;
  #pragma unroll
  for (int k = 0; k < 8; ++k){ float d = v[k] - mean; q += d*d; }
  q += __shfl_xor(q,1); q += __shfl_xor(q,2); q += __shfl_xor(q,4); q += __shfl_xor(q,8);
  float rs = rsqrtf(q*(1.f/128.f) + EPS);
  #pragma unroll
  for (int k = 0; k < 8; ++k)
    buf[row][cg*8 + k] = (v[k] - mean)*rs*gg[cg*8 + k] + bb[cg*8 + k];
}

__global__ __launch_bounds__(512) void tail_kernel(
  const float* __restrict__ pooled,
  const float* __restrict__ Wv, const float* __restrict__ Wo,
  const float* __restrict__ Wlin,
  const float* __restrict__ bv, const float* __restrict__ bo,
  const float* __restrict__ blin,
  const float* __restrict__ g1, const float* __restrict__ b1,
  const float* __restrict__ g2, const float* __restrict__ b2,
  const float* __restrict__ seed, float* __restrict__ out, int G)
{
  __shared__ float ta[16][132];
  __shared__ float tb[16][132];
  const int t = threadIdx.x;
  const int g0 = blockIdx.x * 16;
  const int col = t & 127, rg = t >> 7;   // rg in 0..3 -> 4 rows per thread
  float o[4], res[4];

  if (t < 256){ // load pooled -> ta (same mapping as validated R11 tail)
    int row = t >> 4, ch = t & 15;
    float4 v0 = {0,0,0,0}, v1 = {0,0,0,0};
    if (g0 + row < G){
      const float* src = pooled + (size_t)(g0 + row)*C + ch*8;
      v0 = *(const float4*)(src);
      v1 = *(const float4*)(src + 4);
    }
    *(float4*)&ta[row][ch*8] = v0;
    *(float4*)&ta[row][ch*8 + 4] = v1;
  }
  __syncthreads();

  // P1: y = pooled @ Wo2 + bo2 + seed -> tb ; LN1
  gemmf(ta, Wo + 2*C*C, o, col, rg);
  {
    float ss = seed[col], bb = bo[2*C + col];
    #pragma unroll
    for (int r = 0; r < 4; ++r) tb[rg*4 + r][col] = o[r] + bb + ss;
  }
  __syncthreads();
  if (t < 256) ln16f(tb, g1 + 2*C, b1 + 2*C, t);
  __syncthreads();
  // P2: ta = tb + relu(tb @ Wlin2 + blin2) ; LN2 -> h3 in ta
  gemmf(tb, Wlin + 2*C*C, o, col, rg);
  {
    float bb = blin[2*C + col];
    #pragma unroll
    for (int r = 0; r < 4; ++r) ta[rg*4 + r][col] = tb[rg*4 + r][col] + fmaxf(o[r] + bb, 0.f);
  }
  __syncthreads();
  if (t < 256) ln16f(ta, g2 + 2*C, b2 + 2*C, t);
  __syncthreads();
  // P3: v = h3 @ Wv3 + bv3 -> tb
  gemmf(ta, Wv + 3*C*C, o, col, rg);
  {
    float bb = bv[3*C + col];
    #pragma unroll
    for (int r = 0; r < 4; ++r) tb[rg*4 + r][col] = o[r] + bb;
  }
  __syncthreads();
  // P4: ta = v @ Wo3 + bo3 + h3 ; LN1_3
  gemmf(tb, Wo + 3*C*C, o, col, rg);
  {
    float bb = bo[3*C + col];
    #pragma unroll
    for (int r = 0; r < 4; ++r) res[r] = ta[rg*4 + r][col];
    #pragma unroll
    for (int r = 0; r < 4; ++r) ta[rg*4 + r][col] = o[r] + bb + res[r];
  }
  __syncthreads();
  if (t < 256) ln16f(ta, g1 + 3*C, b1 + 3*C, t);
  __syncthreads();
  // P5: tb = ta + relu(ta @ Wlin3 + blin3) ; LN2_3
  gemmf(ta, Wlin + 3*C*C, o, col, rg);
  {
    float bb = blin[3*C + col];
    #pragma unroll
    for (int r = 0; r < 4; ++r) tb[rg*4 + r][col] = ta[rg*4 + r][col] + fmaxf(o[r] + bb, 0.f);
  }
  __syncthreads();
  if (t < 256) ln16f(tb, g2 + 3*C, b2 + 3*C, t);
  __syncthreads();
  // P6: nan_to_num + store
  for (int idx = t; idx < 16*128; idx += 512){
    int row = idx >> 7, cc = idx & 127;
    if (g0 + row < G){
      float v = tb[row][cc];
      if (isnan(v)) v = 0.f;
      else if (isinf(v)) v = v > 0 ? 3.402823466e38f : -3.402823466e38f;
      out[(size_t)(g0 + row)*C + cc] = v;
    }
  }
}

extern "C" void kernel_launch(void* const* d_in, const int* in_sizes, int n_in,
                              void* d_out, int out_size, void* d_ws, size_t ws_size,
                              hipStream_t stream){
  const float* RF   = (const float*)d_in[0];
  const float* Wq   = (const float*)d_in[1];
  const float* Wk   = (const float*)d_in[2];
  const float* Wv   = (const float*)d_in[3];
  const float* Wo   = (const float*)d_in[4];
  const float* bq   = (const float*)d_in[5];
  const float* bk   = (const float*)d_in[6];
  const float* bv   = (const float*)d_in[7];
  const float* bo   = (const float*)d_in[8];
  const float* Wlin = (const float*)d_in[9];
  const float* blin = (const float*)d_in[10];
  const float* g1   = (const float*)d_in[11];
  const float* b1   = (const float*)d_in[12];
  const float* g2   = (const float*)d_in[13];
  const float* b2   = (const float*)d_in[14];
  const float* seed = (const float*)d_in[15];
  const int* rxn    = (const int*)d_in[16];
  const int* gidx   = (const int*)d_in[17];

  int E = in_sizes[16];
  int G = out_size / C;

  // ws layout
  char* base = (char*)d_ws;
  short* wfrag = (short*)base;                             // 655360 B
  float* qrow  = (float*)(base + 655360);                  // 512 B
  int*   meta  = (int*)(base + 655872);                    // 64 B: [0]=nbins, [1..4]=cnt
  int*   starts= (int*)(base + 655936);                    // 4G
  int*   counts= (int*)(base + 655936 + (size_t)4*G);      // 4G
  int*   gcr   = (int*)(base + 655936 + (size_t)8*G);      // 4G
  int*   binfo = (int*)(base + 655936 + (size_t)12*G);     // 16G
  float* pooled= (float*)(base + 655936 + (size_t)28*G);   // 512G

  hipMemsetAsync(meta, 0, 64, stream);
  hipMemsetAsync(binfo, 0xFF, (size_t)16*G, stream);
  prep_wfrag<<<640, 64, 0, stream>>>(Wq, Wk, Wv, Wo, Wlin, wfrag);
  prep_qrow<<<1, 128, 0, stream>>>(seed, Wq, bq, qrow);
  seg_kernel<<<(G + 255)/256, 256, 0, stream>>>(gidx, E, G, starts, counts, meta + 1, gcr);
  fill_kernel<<<(G + 255)/256, 256, 0, stream>>>(G, meta + 1, gcr, binfo, meta);
  gene_bin_kernel<<<G, 256, 0, stream>>>(RF, wfrag, qrow, bq, bk, bv, bo, blin,
      g1, b1, g2, b2, rxn, starts, counts, binfo, meta, pooled);
  tail_kernel<<<(G + 15)/16, 512, 0, stream>>>(pooled, Wv, Wo, Wlin, bv, bo, blin,
      g1, b1, g2, b2, seed, (float*)d_out, G);
}

// Round 14
// 251.260 us; speedup vs baseline: 1.2259x; 1.0397x over previous
//
#include <hip/hip_runtime.h>
#include <hip/hip_bf16.h>
#include <math.h>

#define C 128
#define H 4
#define LMAX 64
#define EPS 1e-5f
#define ISQ 0.17677669529663687f   // 1/sqrt(32)

using short8  = __attribute__((ext_vector_type(8))) short;
using short4v = __attribute__((ext_vector_type(4))) short;
using f32x4   = __attribute__((ext_vector_type(4))) float;

__device__ __forceinline__ float wsum(float v){
  #pragma unroll
  for (int o = 32; o > 0; o >>= 1) v += __shfl_xor(v, o, 64);
  return v;
}
__device__ __forceinline__ float wmax(float v){
  #pragma unroll
  for (int o = 32; o > 0; o >>= 1) v = fmaxf(v, __shfl_xor(v, o, 64));
  return v;
}
__device__ __forceinline__ short f2bs(float f){
  __hip_bfloat16 b = __float2bfloat16(f);   // RNE
  union { __hip_bfloat16 b; short u; } cv; cv.b = b; return cv.u;
}
__device__ __forceinline__ float b2f(short u){
  return __uint_as_float(((unsigned)(unsigned short)u) << 16);
}

// ---- weight fragments: B-operand layout for mfma_f32_16x16x32_bf16 ----
// lane l, j -> W[kt*32 + (l>>4)*8 + j][nt*16 + (l&15)]
__global__ void prep_wfrag(const float* __restrict__ Wq, const float* __restrict__ Wk,
                           const float* __restrict__ Wv, const float* __restrict__ Wo,
                           const float* __restrict__ Wlin, short* __restrict__ wf){
  int bid = blockIdx.x, l = threadIdx.x;
  int tile = bid & 31, mb = bid >> 5;       // mb = mat*4+blk, 0..19
  int mat = mb >> 2, blk = mb & 3;
  const float* W = (mat==0?Wq : mat==1?Wk : mat==2?Wv : mat==3?Wo : Wlin) + blk*C*C;
  int nt = tile >> 2, kt = tile & 3;
  int col = nt*16 + (l & 15);
  int k0  = kt*32 + ((l >> 4) << 3);
  short8 v;
  #pragma unroll
  for (int j = 0; j < 8; j++) v[j] = f2bs(W[(k0 + j)*C + col]);
  *(short8*)(wf + ((size_t)mb*32 + tile)*512 + (size_t)l*8) = v;
}

__global__ void prep_qrow(const float* __restrict__ seed, const float* __restrict__ Wq,
                          const float* __restrict__ bq, float* __restrict__ qrow){
  int t = threadIdx.x;
  const float* wq2 = Wq + 2*C*C;
  float acc = bq[2*C + t];
  #pragma unroll 4
  for (int k = 0; k < C; k++) acc = fmaf(seed[k], wq2[k*C + t], acc);
  qrow[t] = acc;
}

// ---- segment bounds + class ranks ----
__global__ void seg_kernel(const int* __restrict__ gidx, int E, int G,
                           int* __restrict__ starts, int* __restrict__ counts,
                           int* __restrict__ cnt, int* __restrict__ gcr){
  int g = blockIdx.x * blockDim.x + threadIdx.x;
  if (g >= G) return;
  int lo = 0, hi = E;
  while (lo < hi){ int m = (lo + hi) >> 1; if (gidx[m] < g) lo = m + 1; else hi = m; }
  int s = lo; hi = E;
  while (lo < hi){ int m = (lo + hi) >> 1; if (gidx[m] < g + 1) lo = m + 1; else hi = m; }
  starts[g] = s;
  int c_ = lo - s; counts[g] = c_;
  int L = c_ > LMAX ? LMAX : c_; if (L < 1) L = 1;
  int cl = (L - 1) >> 4;
  int r = atomicAdd(&cnt[cl], 1);
  gcr[g] = (cl << 28) | r;
}

// ---- bin assignment from class ranks (deterministic per gene output) ----
__global__ void fill_kernel(int G, const int* __restrict__ cnt, const int* __restrict__ gcr,
                            int* __restrict__ binfo, int* __restrict__ nbins){
  int g = blockIdx.x * blockDim.x + threadIdx.x;
  if (g >= G) return;
  int nb1 = (cnt[0] + 3) >> 2, nb2 = (cnt[1] + 1) >> 1, nb3 = cnt[2];
  if (g == 0) *nbins = nb1 + nb2 + nb3 + cnt[3];
  int v = gcr[g]; int cl = v >> 28; int r = v & 0x0FFFFFFF;
  int bin, slot;
  if      (cl == 0){ bin = r >> 2;             slot = r & 3; }
  else if (cl == 1){ bin = nb1 + (r >> 1);     slot = (r & 1) * 2; }
  else if (cl == 2){ bin = nb1 + nb2 + r;      slot = 0; }
  else             { bin = nb1 + nb2 + nb3 + r; slot = 0; }
  binfo[bin*4 + slot] = g;
}

__device__ __forceinline__ f32x4 mfma4(short8 a0, short8 a1, short8 a2, short8 a3,
                                       const short* __restrict__ wf, int nt, int l){
  f32x4 acc = {0.f, 0.f, 0.f, 0.f};
  acc = __builtin_amdgcn_mfma_f32_16x16x32_bf16(a0, *(const short8*)(wf + ((nt*4+0)*64 + l)*8), acc, 0,0,0);
  acc = __builtin_amdgcn_mfma_f32_16x16x32_bf16(a1, *(const short8*)(wf + ((nt*4+1)*64 + l)*8), acc, 0,0,0);
  acc = __builtin_amdgcn_mfma_f32_16x16x32_bf16(a2, *(const short8*)(wf + ((nt*4+2)*64 + l)*8), acc, 0,0,0);
  acc = __builtin_amdgcn_mfma_f32_16x16x32_bf16(a3, *(const short8*)(wf + ((nt*4+3)*64 + l)*8), acc, 0,0,0);
  return acc;
}

// LN over 64 rows x 128 cols: 4 threads per row, shfl_xor(1,2) group reduce.
// row = t>>2 is wave-row-aligned: wave w handles rows [w*16, w*16+16).
__device__ __forceinline__ void ln_rows(const short (*src)[136], short (*dst)[136],
                                        const float* __restrict__ gg,
                                        const float* __restrict__ bb, int t){
  int row = t >> 2, q4 = t & 3;
  float v[32];
  float sm = 0.f;
  #pragma unroll
  for (int kk = 0; kk < 32; ++kk){
    float x = b2f(src[row][q4*32 + kk]);
    v[kk] = x; sm += x;
  }
  sm += __shfl_xor(sm, 1);
  sm += __shfl_xor(sm, 2);
  float mean = sm * (1.f/128.f);
  float s2 = 0.f;
  #pragma unroll
  for (int kk = 0; kk < 32; ++kk){ float d = v[kk] - mean; s2 += d*d; }
  s2 += __shfl_xor(s2, 1);
  s2 += __shfl_xor(s2, 2);
  float rs = rsqrtf(s2*(1.f/128.f) + EPS);
  #pragma unroll
  for (int kk = 0; kk < 32; ++kk){
    int col = q4*32 + kk;
    dst[row][col] = f2bs((v[kk] - mean)*rs*gg[col] + bb[col]);
  }
}

__global__ __launch_bounds__(256, 2) void gene_bin_kernel(
  const float* __restrict__ RF, const short* __restrict__ wfrag,
  const float* __restrict__ qrow,
  const float* __restrict__ bq, const float* __restrict__ bk,
  const float* __restrict__ bv, const float* __restrict__ bo,
  const float* __restrict__ blin,
  const float* __restrict__ g1, const float* __restrict__ b1,
  const float* __restrict__ g2, const float* __restrict__ b2,
  const int* __restrict__ rxn_idx, const int* __restrict__ starts,
  const int* __restrict__ counts, const int* __restrict__ binfo,
  const int* __restrict__ meta, float* __restrict__ pooled)
{
  if ((int)blockIdx.x >= meta[0]) return;
  __shared__ short xb[64][136];            // activations (residual source)
  __shared__ short qb[64][136];            // Q, then attn-out (wave-row-private between barA..barD)
  __shared__ short kb[64][136];            // K, then FF temp, then PMA K
  __shared__ short vt[128][72];            // V^T: vt[d][key]
  __shared__ __align__(16) short sc[64][72]; // logits -> probs (wave-row-private); later fp32 PMA probs
  __shared__ float qrl[C];
  __shared__ int mg[4], mL[4], ms0[4], mbase[4];

  const int bin = blockIdx.x;
  const int t = threadIdx.x, w = t >> 6, l = t & 63;
  const int hi = l >> 4, c = l & 15;

  if (t == 0){
    int s = 0;
    while (s < 4){
      int g = binfo[bin*4 + s];
      if (g >= 0){
        int Lg = counts[g]; if (Lg > LMAX) Lg = LMAX;
        int ntg = (Lg + 15) >> 4;
        for (int u = 0; u < ntg; ++u){ mg[s+u] = g; mL[s+u] = Lg; ms0[s+u] = starts[g]; mbase[s+u] = s; }
        s += ntg;
      } else { mg[s] = -1; mL[s] = 0; ms0[s] = 0; mbase[s] = s; s++; }
    }
  }
  if (t < C) qrl[t] = qrow[t];
  __syncthreads();

  // ---- stage rows (bf16), zero pads; zero sc once (cross-gene cols stay 0 forever) ----
  for (int idx = t; idx < 64*16; idx += 256){
    int row = idx >> 4, ch = idx & 15;
    int s = row >> 4;
    int g = mg[s];
    int ro = row - mbase[s]*16;
    short8 u = {0,0,0,0,0,0,0,0};
    if (g >= 0 && ro < mL[s]){
      int rr = rxn_idx[ms0[s] + ro];
      const float* src = RF + (size_t)rr*C + ch*8;
      float4 v0 = *(const float4*)(src);
      float4 v1 = *(const float4*)(src + 4);
      u[0]=f2bs(v0.x); u[1]=f2bs(v0.y); u[2]=f2bs(v0.z); u[3]=f2bs(v0.w);
      u[4]=f2bs(v1.x); u[5]=f2bs(v1.y); u[6]=f2bs(v1.z); u[7]=f2bs(v1.w);
    }
    *(short8*)&xb[row][ch*8] = u;
  }
  {
    short8 z = {0,0,0,0,0,0,0,0};
    for (int idx = t; idx < 64*9; idx += 256){
      int row = idx / 9, ch = idx - row*9;
      *(short8*)&sc[row][ch*8] = z;
    }
  }
  __syncthreads();

  const int myg = mg[w];

  // ================= encoder SABs (blk 0,1) =================
  for (int blk = 0; blk < 2; ++blk){
    // ---- QKV projections (nt-split across waves) ----
    {
      short8 ax[4][4];
      #pragma unroll
      for (int mt = 0; mt < 4; ++mt)
        #pragma unroll
        for (int kk = 0; kk < 4; ++kk)
          ax[mt][kk] = *(const short8*)&xb[mt*16 + c][kk*32 + hi*8];
      #pragma unroll
      for (int i = 0; i < 6; ++i){
        int pr = w + 4*i;                 // 0..23 = (mat 0..2) x (nt 0..7)
        int mat = pr >> 3, nt = pr & 7;
        const short* wfm = wfrag + (size_t)(mat*4 + blk)*16384;
        const float* bias = (mat == 0 ? bq : mat == 1 ? bk : bv);
        int col = nt*16 + c;
        float bb = bias[blk*C + col];
        #pragma unroll
        for (int mt = 0; mt < 4; ++mt){
          f32x4 acc = mfma4(ax[mt][0], ax[mt][1], ax[mt][2], ax[mt][3], wfm, nt, l);
          if (mat == 2){
            short4v pk;
            #pragma unroll
            for (int r = 0; r < 4; r++) pk[r] = f2bs(acc[r] + bb);
            *(short4v*)&vt[col][mt*16 + hi*4] = pk;     // transposed
          } else if (mat == 0){
            #pragma unroll
            for (int r = 0; r < 4; r++) qb[mt*16 + hi*4 + r][col] = f2bs(acc[r] + bb);
          } else {
            #pragma unroll
            for (int r = 0; r < 4; r++) kb[mt*16 + hi*4 + r][col] = f2bs(acc[r] + bb);
          }
        }
      }
    }
    __syncthreads();   // bar A: Q,K,V visible block-wide

    // ---- attention: wave w owns row-block mt=w -> whole head loop is wave-private ----
    for (int h = 0; h < H; ++h){
      if (myg >= 0){
        short8 a = *(const short8*)&qb[w*16 + c][h*32 + hi*8];
        #pragma unroll
        for (int kt = 0; kt < 4; ++kt){
          if (mg[kt] == myg){
            short8 b = *(const short8*)&kb[kt*16 + c][h*32 + hi*8];
            f32x4 acc = {0.f, 0.f, 0.f, 0.f};
            acc = __builtin_amdgcn_mfma_f32_16x16x32_bf16(a, b, acc, 0,0,0);
            #pragma unroll
            for (int r = 0; r < 4; r++) sc[w*16 + hi*4 + r][kt*16 + c] = f2bs(acc[r] * ISQ);
          }
        }
      }
      // masked softmax in-place: row = t>>2 (wave-row-local)
      {
        int row = t >> 2, q4 = t & 3;
        int s = row >> 4;
        if (mg[s] >= 0){
          int kbeg = mbase[s]*16;
          int kend = kbeg + mL[s];
          int send = kbeg + (((mL[s] + 15) >> 4) << 4);
          int b0 = q4*16;
          float e[16];
          float mx = -3.4e38f;
          #pragma unroll
          for (int kk = 0; kk < 16; ++kk){
            int col = b0 + kk;
            bool ok = (col >= kbeg) && (col < kend);
            float lg = ok ? b2f(sc[row][col]) : -3.4e38f;
            e[kk] = lg;
            mx = fmaxf(mx, lg);
          }
          mx = fmaxf(mx, __shfl_xor(mx, 1));
          mx = fmaxf(mx, __shfl_xor(mx, 2));
          float sm = 0.f;
          #pragma unroll
          for (int kk = 0; kk < 16; ++kk){
            int col = b0 + kk;
            bool ok = (col >= kbeg) && (col < kend);
            float ee = ok ? __expf(e[kk] - mx) : 0.f;
            e[kk] = ee; sm += ee;
          }
          sm += __shfl_xor(sm, 1);
          sm += __shfl_xor(sm, 2);
          float inv = 1.f / sm;
          #pragma unroll
          for (int kk = 0; kk < 16; ++kk){
            int col = b0 + kk;
            if (col >= kbeg && col < send)
              sc[row][col] = f2bs((col < kend) ? e[kk]*inv : 0.f);
          }
        }
      }
      // PV: wave w owns mt=w
      if (myg >= 0){
        #pragma unroll
        for (int dt = 0; dt < 2; ++dt){
          f32x4 acc = {0.f, 0.f, 0.f, 0.f};
          #pragma unroll
          for (int ks = 0; ks < 2; ++ks){
            short8 a = *(const short8*)&sc[w*16 + c][ks*32 + hi*8];
            short8 b = *(const short8*)&vt[h*32 + dt*16 + c][ks*32 + hi*8];
            acc = __builtin_amdgcn_mfma_f32_16x16x32_bf16(a, b, acc, 0,0,0);
          }
          int col = h*32 + dt*16 + c;
          #pragma unroll
          for (int r = 0; r < 4; r++) qb[w*16 + hi*4 + r][col] = f2bs(acc[r]);
        }
      }
    }
    __syncthreads();   // bar D: attn-out (qb) all rows visible; all kb score-reads done

    // ---- Wo + bo + residual -> xb (nt-split; same per-element mfma4/bias/residual math) ----
    {
      short8 aq[4][4];
      #pragma unroll
      for (int mt = 0; mt < 4; ++mt)
        #pragma unroll
        for (int kk = 0; kk < 4; ++kk)
          aq[mt][kk] = *(const short8*)&qb[mt*16 + c][kk*32 + hi*8];
      const short* wfo = wfrag + (size_t)(3*4 + blk)*16384;
      #pragma unroll
      for (int i = 0; i < 2; ++i){
        int nt = w + 4*i;
        int col = nt*16 + c;
        float bb = bo[blk*C + col];
        #pragma unroll
        for (int mt = 0; mt < 4; ++mt){
          f32x4 acc = mfma4(aq[mt][0], aq[mt][1], aq[mt][2], aq[mt][3], wfo, nt, l);
          #pragma unroll
          for (int r = 0; r < 4; r++){
            int row = mt*16 + hi*4 + r;
            xb[row][col] = f2bs(acc[r] + bb + b2f(xb[row][col]));
          }
        }
      }
    }
    __syncthreads();   // bar E: xb fully updated (all cols)
    ln_rows(xb, xb, g1 + blk*C, b1 + blk*C, t);
    __syncthreads();   // bar F: post-LN1 xb visible to all waves (FF reads all rows)

    // ---- FF -> kb (nt-split) ----
    {
      short8 af[4][4];
      #pragma unroll
      for (int mt = 0; mt < 4; ++mt)
        #pragma unroll
        for (int kk = 0; kk < 4; ++kk)
          af[mt][kk] = *(const short8*)&xb[mt*16 + c][kk*32 + hi*8];
      const short* wfl = wfrag + (size_t)(4*4 + blk)*16384;
      #pragma unroll
      for (int i = 0; i < 2; ++i){
        int nt = w + 4*i;
        int col = nt*16 + c;
        float bb = blin[blk*C + col];
        #pragma unroll
        for (int mt = 0; mt < 4; ++mt){
          f32x4 acc = mfma4(af[mt][0], af[mt][1], af[mt][2], af[mt][3], wfl, nt, l);
          #pragma unroll
          for (int r = 0; r < 4; r++){
            int row = mt*16 + hi*4 + r;
            kb[row][col] = f2bs(b2f(xb[row][col]) + fmaxf(acc[r] + bb, 0.f));
          }
        }
      }
    }
    __syncthreads();   // bar G: kb complete (LN2 reads all cols of own rows)
    ln_rows(kb, xb, g2 + blk*C, b2 + blk*C, t);
    __syncthreads();   // bar C: next layer's QKV reads ALL xb rows
  }

  // ================= PMA: K,V projections (nt-split) + per-gene pooling =================
  {
    short8 ap[4][4];
    #pragma unroll
    for (int mt = 0; mt < 4; ++mt)
      #pragma unroll
      for (int kk = 0; kk < 4; ++kk)
        ap[mt][kk] = *(const short8*)&xb[mt*16 + c][kk*32 + hi*8];
    const short* wfk2 = wfrag + (size_t)(1*4 + 2)*16384;
    const short* wfv2 = wfrag + (size_t)(2*4 + 2)*16384;
    #pragma unroll
    for (int i = 0; i < 4; ++i){
      int pr = w + 4*i;                 // 0..15 = (mat 0..1) x (nt 0..7)
      int mat = pr >> 3, nt = pr & 7;
      const short* wfm = mat ? wfv2 : wfk2;
      const float* bias = mat ? bv : bk;
      int col = nt*16 + c;
      float bb = bias[2*C + col];
      #pragma unroll
      for (int mt = 0; mt < 4; ++mt){
        f32x4 acc = mfma4(ap[mt][0], ap[mt][1], ap[mt][2], ap[mt][3], wfm, nt, l);
        if (!mat){
          #pragma unroll
          for (int r = 0; r < 4; r++) kb[mt*16 + hi*4 + r][col] = f2bs(acc[r] + bb);
        } else {
          short4v pk;
          #pragma unroll
          for (int r = 0; r < 4; r++) pk[r] = f2bs(acc[r] + bb);
          *(short4v*)&vt[col][mt*16 + hi*4] = pk;
        }
      }
    }
  }
  __syncthreads();   // bar A': K',V' visible (pooling reads cross-wave rows/cols)
  // pooling: wave w = slot w (if base slot of a gene)
  {
    int g = mg[w];
    if (g >= 0 && mbase[w] == w){
      int L = mL[w];
      int row = w*16 + l;                // key row in kb / key col in vt
      float* ps = (float*)&sc[0][0];     // sc dead: alias as fp32 probs [slot*4+h][64]
      #pragma unroll
      for (int h = 0; h < 4; ++h){
        float a = -3.4e38f;
        if (l < L){
          float acc = 0.f;
          #pragma unroll 8
          for (int dd = 0; dd < 32; ++dd)
            acc = fmaf(b2f(kb[row][h*32 + dd]), qrl[h*32 + dd], acc);
          a = acc * ISQ;
        }
        float mx = wmax(a);
        float e = (l < L) ? __expf(a - mx) : 0.f;
        float s = wsum(e);
        ps[(w*4 + h)*64 + l] = e / s;
      }
      #pragma unroll
      for (int half = 0; half < 2; ++half){
        int d = l + half*64;
        int h = d >> 5;
        float acc = 0.f;
        for (int kk = 0; kk < L; ++kk)
          acc = fmaf(ps[(w*4 + h)*64 + kk], b2f(vt[d][w*16 + kk]), acc);
        pooled[(size_t)g*C + d] = acc;
      }
    }
  }
}

// ================= fp32 batched tail: PMA post-attn + decoder SAB (16 genes/block, 8 waves) =================
__device__ __forceinline__ void gemmf(const float (*src)[132], const float* __restrict__ W,
                                      float (&o)[4], int col, int rg){
  #pragma unroll
  for (int r = 0; r < 4; ++r) o[r] = 0.f;
  #pragma unroll 8
  for (int k = 0; k < 128; ++k){
    float wv = W[k*C + col];
    #pragma unroll
    for (int r = 0; r < 4; ++r) o[r] = fmaf(src[rg*4 + r][k], wv, o[r]);
  }
}

__device__ __forceinline__ void ln16f(float (*buf)[132], const float* __restrict__ gg,
                                      const float* __restrict__ bb, int t){
  int row = t >> 4, cg = t & 15;
  float v[8]; float s = 0.f;
  #pragma unroll
  for (int k = 0; k < 8; ++k){ v[k] = buf[row][cg*8 + k]; s += v[k]; }
  s += __shfl_xor(s,1); s += __shfl_xor(s,2); s += __shfl_xor(s,4); s += __shfl_xor(s,8);
  float mean = s * (1.f/128.f);
  float q = 0.f;
  #pragma unroll
  for (int k = 0; k < 8; ++k){ float d = v[k] - mean; q += d*d; }
  q += __shfl_xor(q,1); q += __shfl_xor(q,2); q += __shfl_xor(q,4); q += __shfl_xor(q,8);
  float rs = rsqrtf(q*(1.f/128.f) + EPS);
  #pragma unroll
  for (int k = 0; k < 8; ++k)
    buf[row][cg*8 + k] = (v[k] - mean)*rs*gg[cg*8 + k] + bb[cg*8 + k];
}

__global__ __launch_bounds__(512) void tail_kernel(
  const float* __restrict__ pooled,
  const float* __restrict__ Wv, const float* __restrict__ Wo,
  const float* __restrict__ Wlin,
  const float* __restrict__ bv, const float* __restrict__ bo,
  const float* __restrict__ blin,
  const float* __restrict__ g1, const float* __restrict__ b1,
  const float* __restrict__ g2, const float* __restrict__ b2,
  const float* __restrict__ seed, float* __restrict__ out, int G)
{
  __shared__ float ta[16][132];
  __shared__ float tb[16][132];
  const int t = threadIdx.x;
  const int g0 = blockIdx.x * 16;
  const int col = t & 127, rg = t >> 7;   // rg in 0..3 -> 4 rows per thread
  float o[4], res[4];

  if (t < 256){ // load pooled -> ta
    int row = t >> 4, ch = t & 15;
    float4 v0 = {0,0,0,0}, v1 = {0,0,0,0};
    if (g0 + row < G){
      const float* src = pooled + (size_t)(g0 + row)*C + ch*8;
      v0 = *(const float4*)(src);
      v1 = *(const float4*)(src + 4);
    }
    *(float4*)&ta[row][ch*8] = v0;
    *(float4*)&ta[row][ch*8 + 4] = v1;
  }
  __syncthreads();

  // P1: y = pooled @ Wo2 + bo2 + seed -> tb ; LN1
  gemmf(ta, Wo + 2*C*C, o, col, rg);
  {
    float ss = seed[col], bb = bo[2*C + col];
    #pragma unroll
    for (int r = 0; r < 4; ++r) tb[rg*4 + r][col] = o[r] + bb + ss;
  }
  __syncthreads();
  if (t < 256) ln16f(tb, g1 + 2*C, b1 + 2*C, t);
  __syncthreads();
  // P2: ta = tb + relu(tb @ Wlin2 + blin2) ; LN2 -> h3 in ta
  gemmf(tb, Wlin + 2*C*C, o, col, rg);
  {
    float bb = blin[2*C + col];
    #pragma unroll
    for (int r = 0; r < 4; ++r) ta[rg*4 + r][col] = tb[rg*4 + r][col] + fmaxf(o[r] + bb, 0.f);
  }
  __syncthreads();
  if (t < 256) ln16f(ta, g2 + 2*C, b2 + 2*C, t);
  __syncthreads();
  // P3: v = h3 @ Wv3 + bv3 -> tb
  gemmf(ta, Wv + 3*C*C, o, col, rg);
  {
    float bb = bv[3*C + col];
    #pragma unroll
    for (int r = 0; r < 4; ++r) tb[rg*4 + r][col] = o[r] + bb;
  }
  __syncthreads();
  // P4: ta = v @ Wo3 + bo3 + h3 ; LN1_3
  gemmf(tb, Wo + 3*C*C, o, col, rg);
  {
    float bb = bo[3*C + col];
    #pragma unroll
    for (int r = 0; r < 4; ++r) res[r] = ta[rg*4 + r][col];
    #pragma unroll
    for (int r = 0; r < 4; ++r) ta[rg*4 + r][col] = o[r] + bb + res[r];
  }
  __syncthreads();
  if (t < 256) ln16f(ta, g1 + 3*C, b1 + 3*C, t);
  __syncthreads();
  // P5: tb = ta + relu(ta @ Wlin3 + blin3) ; LN2_3
  gemmf(ta, Wlin + 3*C*C, o, col, rg);
  {
    float bb = blin[3*C + col];
    #pragma unroll
    for (int r = 0; r < 4; ++r) tb[rg*4 + r][col] = ta[rg*4 + r][col] + fmaxf(o[r] + bb, 0.f);
  }
  __syncthreads();
  if (t < 256) ln16f(tb, g2 + 3*C, b2 + 3*C, t);
  __syncthreads();
  // P6: nan_to_num + store
  for (int idx = t; idx < 16*128; idx += 512){
    int row = idx >> 7, cc = idx & 127;
    if (g0 + row < G){
      float v = tb[row][cc];
      if (isnan(v)) v = 0.f;
      else if (isinf(v)) v = v > 0 ? 3.402823466e38f : -3.402823466e38f;
      out[(size_t)(g0 + row)*C + cc] = v;
    }
  }
}

extern "C" void kernel_launch(void* const* d_in, const int* in_sizes, int n_in,
                              void* d_out, int out_size, void* d_ws, size_t ws_size,
                              hipStream_t stream){
  const float* RF   = (const float*)d_in[0];
  const float* Wq   = (const float*)d_in[1];
  const float* Wk   = (const float*)d_in[2];
  const float* Wv   = (const float*)d_in[3];
  const float* Wo   = (const float*)d_in[4];
  const float* bq   = (const float*)d_in[5];
  const float* bk   = (const float*)d_in[6];
  const float* bv   = (const float*)d_in[7];
  const float* bo   = (const float*)d_in[8];
  const float* Wlin = (const float*)d_in[9];
  const float* blin = (const float*)d_in[10];
  const float* g1   = (const float*)d_in[11];
  const float* b1   = (const float*)d_in[12];
  const float* g2   = (const float*)d_in[13];
  const float* b2   = (const float*)d_in[14];
  const float* seed = (const float*)d_in[15];
  const int* rxn    = (const int*)d_in[16];
  const int* gidx   = (const int*)d_in[17];

  int E = in_sizes[16];
  int G = out_size / C;

  // ws layout
  char* base = (char*)d_ws;
  short* wfrag = (short*)base;                             // 655360 B
  float* qrow  = (float*)(base + 655360);                  // 512 B
  int*   meta  = (int*)(base + 655872);                    // 64 B: [0]=nbins, [1..4]=cnt
  int*   starts= (int*)(base + 655936);                    // 4G
  int*   counts= (int*)(base + 655936 + (size_t)4*G);      // 4G
  int*   gcr   = (int*)(base + 655936 + (size_t)8*G);      // 4G
  int*   binfo = (int*)(base + 655936 + (size_t)12*G);     // 16G
  float* pooled= (float*)(base + 655936 + (size_t)28*G);   // 512G

  hipMemsetAsync(meta, 0, 64, stream);
  hipMemsetAsync(binfo, 0xFF, (size_t)16*G, stream);
  prep_wfrag<<<640, 64, 0, stream>>>(Wq, Wk, Wv, Wo, Wlin, wfrag);
  prep_qrow<<<1, 128, 0, stream>>>(seed, Wq, bq, qrow);
  seg_kernel<<<(G + 255)/256, 256, 0, stream>>>(gidx, E, G, starts, counts, meta + 1, gcr);
  fill_kernel<<<(G + 255)/256, 256, 0, stream>>>(G, meta + 1, gcr, binfo, meta);
  gene_bin_kernel<<<G, 256, 0, stream>>>(RF, wfrag, qrow, bq, bk, bv, bo, blin,
      g1, b1, g2, b2, rxn, starts, counts, binfo, meta, pooled);
  tail_kernel<<<(G + 15)/16, 512, 0, stream>>>(pooled, Wv, Wo, Wlin, bv, bo, blin,
      g1, b1, g2, b2, seed, (float*)d_out, G);
}